// Round 7
// baseline (174.103 us; speedup 1.0000x reference)
//
#include <hip/hip_runtime.h>
#include <hip/hip_bf16.h>

typedef __attribute__((ext_vector_type(8))) short s16x8;
typedef __attribute__((ext_vector_type(4))) float f32x4;

#define NSLOT 128

__device__ __forceinline__ short f2bf(float f) {
    union { float f; unsigned u; } c; c.f = f;
    unsigned u = c.u;
    return (short)((u + 0x7fffu + ((u >> 16) & 1u)) >> 16);  // RNE
}
__device__ __forceinline__ float bf2f(short s) {
    union { unsigned u; float f; } c;
    c.u = ((unsigned)(unsigned short)s) << 16;
    return c.f;
}
__device__ __forceinline__ unsigned pk2(float lo, float hi) {
    __hip_bfloat162 p = __float22bfloat162_rn(make_float2(lo, hi));
    return *reinterpret_cast<unsigned*>(&p);
}

// global -> LDS direct DMA, 16B per lane
#define GLD16(gp, lp) __builtin_amdgcn_global_load_lds( \
    (const __attribute__((address_space(1))) unsigned int*)(gp), \
    (__attribute__((address_space(3))) unsigned int*)(lp), 16, 0, 0)

// ---------------------------------------------------------------------------
// K1: precompute (unchanged from R6)
//   blocks 0..511: u8[b, c ^ ((b&7)<<3)] = bf16(x[b]@W1a)   (swizzled bf16 U)
//                  V[b,:] = x[b]@W1b (f32) ; 256 elems of swizzled W2
//   block 512:     c0 = q@W1q + g_b1 ; q_exp = relu(relu(q@qe_w1+b1)@qe_w2+b2)
//   blocks 513+:   zero accb
// ---------------------------------------------------------------------------
__global__ __launch_bounds__(256) void rn_k1(
    const float* __restrict__ x, const float* __restrict__ q,
    const float* __restrict__ g_w1, const float* __restrict__ g_b1,
    const float* __restrict__ g_w2,
    const float* __restrict__ qe_w1, const float* __restrict__ qe_b1,
    const float* __restrict__ qe_w2, const float* __restrict__ qe_b2,
    short* __restrict__ u8, float* __restrict__ V,
    float* __restrict__ c0, float* __restrict__ qexp,
    short* __restrict__ w2s, float* __restrict__ accb)
{
    __shared__ float sbuf[64];
    __shared__ float qh[256];
    const int blk = blockIdx.x, t = threadIdx.x;

    if (blk < 512) {
        if (t < 64) sbuf[t] = x[blk * 64 + t];
        __syncthreads();
        float u = 0.f, v = 0.f;
        #pragma unroll 4
        for (int k = 0; k < 64; ++k) {
            float xv = sbuf[k];
            u += xv * g_w1[k * 256 + t];
            v += xv * g_w1[(64 + k) * 256 + t];
        }
        u8[blk * 256 + (t ^ ((blk & 7) << 3))] = f2bf(u);   // swizzled bf16
        V[blk * 256 + t] = v;
        // swizzled W2 (one bf16 element per thread)
        {
            int E = blk * 256 + t;
            int e = E & 7, f = E >> 3;
            int lane = f & 63, n = (f >> 6) & 3, kk = (f >> 8) & 7, wv = (f >> 11) & 3;
            int l15 = lane & 15, g = lane >> 4;
            int col = wv * 64 + n * 16 + l15;
            int k = kk * 32 + g * 8 + e;
            w2s[E] = f2bf(g_w2[k * 256 + col]);
        }
    } else if (blk == 512) {
        if (t < 64) sbuf[t] = q[t];
        __syncthreads();
        float cc = g_b1[t], hh = qe_b1[t];
        #pragma unroll 4
        for (int k = 0; k < 64; ++k) {
            float qv = sbuf[k];
            cc += qv * g_w1[(128 + k) * 256 + t];
            hh += qv * qe_w1[k * 256 + t];
        }
        c0[t] = cc;
        qh[t] = fmaxf(hh, 0.f);
        __syncthreads();
        float qe = qe_b2[t];
        #pragma unroll 4
        for (int k = 0; k < 256; ++k) qe += qh[k] * qe_w2[k * 256 + t];
        qexp[t] = fmaxf(qe, 0.f);
    } else {
        const int total = NSLOT * 257;
        int off = (blk - 513) * 2048 + t * 8;
        #pragma unroll
        for (int i = 0; i < 8; ++i)
            if (off + i < total) accb[off + i] = 0.f;
    }
}

// ---------------------------------------------------------------------------
// K2: PERSISTENT. 1024 blocks x 4 chunks. Single 32KB hT buffer.
// Pipeline: after the post-MFMA barrier of chunk k, issue chunk k+1's DMA +
// V-row loads, then run chunk k's exp/atomic epilogue (latency hidden).
// DMA->build is wave-local (wave w stages segs {w+4i}, its threads build
// exactly those segs), so loop-top s_waitcnt vmcnt(0) is a wave-local guard.
// Cross-wave hazards covered by the two barriers.
// ---------------------------------------------------------------------------
__global__ __launch_bounds__(256, 3) void rn_k2(
    const float* __restrict__ V, const float* __restrict__ c0,
    const float* __restrict__ qexp, const short* __restrict__ u8,
    const short* __restrict__ w2s, const float* __restrict__ g_b2,
    float* __restrict__ accb)
{
    __shared__ short hT[16384];            // 32KB, XOR-swizzled image
    __shared__ float srowT[64][4];         // [row][wave]

    const int bid = blockIdx.x;
    const int tid = threadIdx.x;
    const int wave = tid >> 6, lane = tid & 63;
    const int l15 = lane & 15, g = lane >> 4;
    const int col0 = wave << 6;

    // fixed per block
    float qe[4], b2c[4];
    #pragma unroll
    for (int n = 0; n < 4; ++n) {
        int col = col0 + n * 16 + l15;
        qe[n]  = qexp[col];
        b2c[n] = g_b2[col];
    }
    const int rowb = tid >> 5;                         // 0..7
    const int colb = ((tid & 31) * 8) ^ (rowb << 3);   // unswizzled col base
    float c8[8];
    {
        const float4 cA = *(const float4*)&c0[colb];
        const float4 cB = *(const float4*)&c0[colb + 4];
        c8[0] = cA.x; c8[1] = cA.y; c8[2] = cA.z; c8[3] = cA.w;
        c8[4] = cB.x; c8[5] = cB.y; c8[6] = cB.z; c8[7] = cB.w;
    }
    const short* w2w = w2s + (wave << 14);
    const int axor  = (l15 & 7) << 3;
    const int arow0 = l15 * 256;

    // ---- prologue: stage chunk 0 + vc8 for chunk 0 ----
    float vc8[8];
    {
        const int v0 = bid << 2;
        const short* src = u8 + ((v0 & 7) << 6) * 256;
        #pragma unroll
        for (int i = 0; i < 8; ++i) {
            const int seg = wave + (i << 2);
            GLD16(src + seg * 512 + lane * 8, hT + seg * 512);
        }
        const int a0 = v0 >> 3;
        const float4 vA = *(const float4*)&V[a0 * 256 + colb];
        const float4 vB = *(const float4*)&V[a0 * 256 + colb + 4];
        vc8[0] = vA.x + c8[0]; vc8[1] = vA.y + c8[1];
        vc8[2] = vA.z + c8[2]; vc8[3] = vA.w + c8[3];
        vc8[4] = vB.x + c8[4]; vc8[5] = vB.y + c8[5];
        vc8[6] = vB.z + c8[6]; vc8[7] = vB.w + c8[7];
    }

    for (int k = 0; k < 4; ++k) {
        const int vv = (bid << 2) + k;
        const int slot = vv & (NSLOT - 1);

        asm volatile("s_waitcnt vmcnt(0)" ::: "memory");   // my DMAs + vc8 done
        __builtin_amdgcn_sched_barrier(0);

        // ---- build h in place: h = relu(U + V[a] + c0), bf16 ----
        #pragma unroll
        for (int it = 0; it < 8; ++it) {
            const int si = tid * 8 + it * 2048;
            s16x8 raw = *(const s16x8*)&hT[si];
            float h0 = fmaxf(bf2f(raw[0]) + vc8[0], 0.f);
            float h1 = fmaxf(bf2f(raw[1]) + vc8[1], 0.f);
            float h2 = fmaxf(bf2f(raw[2]) + vc8[2], 0.f);
            float h3 = fmaxf(bf2f(raw[3]) + vc8[3], 0.f);
            float h4 = fmaxf(bf2f(raw[4]) + vc8[4], 0.f);
            float h5 = fmaxf(bf2f(raw[5]) + vc8[5], 0.f);
            float h6 = fmaxf(bf2f(raw[6]) + vc8[6], 0.f);
            float h7 = fmaxf(bf2f(raw[7]) + vc8[7], 0.f);
            uint4 ov;
            ov.x = pk2(h0, h1); ov.y = pk2(h2, h3);
            ov.z = pk2(h4, h5); ov.w = pk2(h6, h7);
            *reinterpret_cast<uint4*>(&hT[si]) = ov;
        }
        __syncthreads();                    // build done (all waves)

        // ---- MFMA: r = h @ W2 ----
#define BFR_LOAD(kk, n) (*(const s16x8*)&w2w[(((kk) * 4 + (n)) << 9) + (lane << 3)])
        f32x4 acc[4][4];
        #pragma unroll
        for (int m = 0; m < 4; ++m)
            #pragma unroll
            for (int n = 0; n < 4; ++n)
                acc[m][n] = (f32x4){0.f, 0.f, 0.f, 0.f};

        #pragma unroll
        for (int kk = 0; kk < 8; ++kk) {
            const int koff = kk * 32 + g * 8;
            s16x8 bfr[4];
            #pragma unroll
            for (int n = 0; n < 4; ++n) bfr[n] = BFR_LOAD(kk, n);
            s16x8 afr[4];
            #pragma unroll
            for (int m = 0; m < 4; ++m)
                afr[m] = *(const s16x8*)&hT[arow0 + m * 4096 + (koff ^ axor)];
            __builtin_amdgcn_s_setprio(1);
            #pragma unroll
            for (int m = 0; m < 4; ++m)
                #pragma unroll
                for (int n = 0; n < 4; ++n)
                    acc[m][n] = __builtin_amdgcn_mfma_f32_16x16x32_bf16(
                        afr[m], bfr[n], acc[m][n], 0, 0, 0);
            __builtin_amdgcn_s_setprio(0);
        }
#undef BFR_LOAD

        // ---- bias + relu, per-wave score partials ----
        #pragma unroll
        for (int m = 0; m < 4; ++m)
            #pragma unroll
            for (int n = 0; n < 4; ++n)
                #pragma unroll
                for (int j = 0; j < 4; ++j)
                    acc[m][n][j] = fmaxf(acc[m][n][j] + b2c[n], 0.f);

        #pragma unroll
        for (int m = 0; m < 4; ++m) {
            #pragma unroll
            for (int j = 0; j < 4; ++j) {
                float sp = 0.f;
                #pragma unroll
                for (int n = 0; n < 4; ++n) sp += acc[m][n][j] * qe[n];
                sp += __shfl_xor(sp, 1);
                sp += __shfl_xor(sp, 2);
                sp += __shfl_xor(sp, 4);
                sp += __shfl_xor(sp, 8);
                if (l15 == 0) srowT[m * 16 + g * 4 + j][wave] = sp;
            }
        }
        __syncthreads();                    // all hT reads done + srowT ready

        // ---- prefetch chunk k+1 (DMA + vc8) under the epilogue ----
        if (k < 3) {
            const int vn = vv + 1;
            const short* srcn = u8 + ((vn & 7) << 6) * 256;
            #pragma unroll
            for (int i = 0; i < 8; ++i) {
                const int seg = wave + (i << 2);
                GLD16(srcn + seg * 512 + lane * 8, hT + seg * 512);
            }
            const int an = vn >> 3;
            const float4 vA = *(const float4*)&V[an * 256 + colb];
            const float4 vB = *(const float4*)&V[an * 256 + colb + 4];
            vc8[0] = vA.x + c8[0]; vc8[1] = vA.y + c8[1];
            vc8[2] = vA.z + c8[2]; vc8[3] = vA.w + c8[3];
            vc8[4] = vB.x + c8[4]; vc8[5] = vB.y + c8[5];
            vc8[6] = vB.z + c8[6]; vc8[7] = vB.w + c8[7];
        }

        // ---- exp weights + reductions + atomics ----
        float wrow[4][4];
        #pragma unroll
        for (int m = 0; m < 4; ++m)
            #pragma unroll
            for (int j = 0; j < 4; ++j) {
                const float4 s4 = *(const float4*)&srowT[m * 16 + g * 4 + j][0];
                wrow[m][j] = __expf(s4.x + s4.y + s4.z + s4.w);  // s>=0, bounded
            }

        if (wave == 0) {
            float ls = 0.f;
            #pragma unroll
            for (int m = 0; m < 4; ++m)
                #pragma unroll
                for (int j = 0; j < 4; ++j) ls += wrow[m][j];
            ls += __shfl_xor(ls, 16);
            ls += __shfl_xor(ls, 32);
            if (lane == 0) atomicAdd(&accb[slot * 257 + 256], ls);
        }

        #pragma unroll
        for (int n = 0; n < 4; ++n) {
            float wv = 0.f;
            #pragma unroll
            for (int m = 0; m < 4; ++m)
                #pragma unroll
                for (int j = 0; j < 4; ++j)
                    wv += wrow[m][j] * acc[m][n][j];
            wv += __shfl_xor(wv, 16);
            wv += __shfl_xor(wv, 32);
            if (lane < 16) atomicAdd(&accb[slot * 257 + col0 + n * 16 + lane], wv);
        }
    }
}

// ---------------------------------------------------------------------------
// K4: merge NSLOT slots -> embedding -> f MLP -> out[64]
// 1024 threads: 4-way K-split per layer + LDS reduce (parallel weight loads).
// ---------------------------------------------------------------------------
__global__ __launch_bounds__(1024) void rn_k4(
    const float* __restrict__ accb,
    const float* __restrict__ f_w1, const float* __restrict__ f_b1,
    const float* __restrict__ f_w2, const float* __restrict__ f_b2,
    float* __restrict__ out)
{
    __shared__ float part[4][256];
    __shared__ float emb[256];
    __shared__ float fh[256];
    __shared__ float lsa[128];
    const int t   = threadIdx.x;
    const int col = t & 255;
    const int sl  = t >> 8;                 // 0..3

    // slot merge (each (sl,col) sums 32 slots)
    float v = 0.f;
    #pragma unroll 8
    for (int s = sl; s < NSLOT; s += 4) v += accb[s * 257 + col];
    part[sl][col] = v;
    if (t < 128) lsa[t] = accb[t * 257 + 256];
    __syncthreads();

    if (sl == 0) {
        float ls = 0.f;
        #pragma unroll 8
        for (int s = 0; s < 128; ++s) ls += lsa[s];     // broadcast reads
        emb[col] = (part[0][col] + part[1][col] + part[2][col] + part[3][col]) / ls;
    }
    __syncthreads();

    // f layer 1: K-split by sl
    {
        float h = 0.f;
        const int k0 = sl << 6;
        #pragma unroll 8
        for (int k = 0; k < 64; ++k)
            h += emb[k0 + k] * f_w1[(k0 + k) * 256 + col];
        part[sl][col] = h;
    }
    __syncthreads();
    if (sl == 0)
        fh[col] = fmaxf(part[0][col] + part[1][col] + part[2][col] + part[3][col]
                        + f_b1[col], 0.f);
    __syncthreads();

    // f layer 2: out 64 cols, K-split by t>>6 (threads 0..255)
    if (t < 256) {
        const int oc = t & 63, ks = t >> 6;
        float o = 0.f;
        const int k0 = ks << 6;
        #pragma unroll 8
        for (int k = 0; k < 64; ++k)
            o += fh[k0 + k] * f_w2[(k0 + k) * 64 + oc];
        part[ks][oc] = o;
    }
    __syncthreads();
    if (t < 64)
        out[t] = part[0][t] + part[1][t] + part[2][t] + part[3][t] + f_b2[t];
}

extern "C" void kernel_launch(void* const* d_in, const int* in_sizes, int n_in,
                              void* d_out, int out_size, void* d_ws, size_t ws_size,
                              hipStream_t stream) {
    const float* x     = (const float*)d_in[0];
    const float* q     = (const float*)d_in[1];
    const float* g_w1  = (const float*)d_in[2];
    const float* g_b1  = (const float*)d_in[3];
    const float* g_w2  = (const float*)d_in[4];
    const float* g_b2  = (const float*)d_in[5];
    const float* qe_w1 = (const float*)d_in[6];
    const float* qe_b1 = (const float*)d_in[7];
    const float* qe_w2 = (const float*)d_in[8];
    const float* qe_b2 = (const float*)d_in[9];
    const float* f_w1  = (const float*)d_in[10];
    const float* f_b1  = (const float*)d_in[11];
    const float* f_w2  = (const float*)d_in[12];
    const float* f_b2  = (const float*)d_in[13];

    float* wsf  = (float*)d_ws;
    short* u8   = (short*)wsf;             // 512*256 bf16 (swizzled)
    float* V    = wsf + 65536;             // 512*256 f32
    float* c0   = wsf + 196608;            // 256
    float* qexp = wsf + 196864;            // 256
    short* w2s  = (short*)(wsf + 197120);  // 256*256 bf16 (swizzled)
    float* accb = wsf + 229888;            // NSLOT slots * 257 floats

    hipLaunchKernelGGL(rn_k1, dim3(530), dim3(256), 0, stream,
                       x, q, g_w1, g_b1, g_w2, qe_w1, qe_b1, qe_w2, qe_b2,
                       u8, V, c0, qexp, w2s, accb);
    hipLaunchKernelGGL(rn_k2, dim3(1024), dim3(256), 0, stream,
                       V, c0, qexp, (const short*)u8, (const short*)w2s, g_b2, accb);
    hipLaunchKernelGGL(rn_k4, dim3(1), dim3(1024), 0, stream,
                       accb, f_w1, f_b1, f_w2, f_b2, (float*)d_out);
}

// Round 8
// 72.585 us; speedup vs baseline: 2.3986x; 2.3986x over previous
//
#include <hip/hip_runtime.h>
#include <hip/hip_bf16.h>

typedef __attribute__((ext_vector_type(8))) short s16x8;
typedef __attribute__((ext_vector_type(4))) float f32x4;

#define NSLOT 128

__device__ __forceinline__ short f2bf(float f) {
    union { float f; unsigned u; } c; c.f = f;
    unsigned u = c.u;
    return (short)((u + 0x7fffu + ((u >> 16) & 1u)) >> 16);  // RNE
}

// ---------------------------------------------------------------------------
// K1: precompute, GEMM-restructured (no redundant W1 re-reads).
//   blocks 0..63:   UV GEMM. rg=blk>>1, half=blk&1. 16 x-rows, 256 cols.
//                   W1 column-slice (64 f32) held in registers, x-tile in LDS.
//                   half 0 -> U, half 1 -> V.
//   block 64:       c0 = q@W1q + g_b1 ; q_exp = relu(relu(q@qe_w1+b1)@qe_w2+b2)
//   blocks 65..96:  w2s swizzle, scatter-write (coalesced g_w2 reads)
//   blocks 97..113: zero accb
// w2s layout: w2s[(((wv*8+kk)*4+n)*64+lane)*8+e] = bf16(g_w2[k*256+col]),
//   col = wv*64+n*16+(lane&15), k = kk*32+(lane>>4)*8+e
// ---------------------------------------------------------------------------
__global__ __launch_bounds__(256) void rn_k1(
    const float* __restrict__ x, const float* __restrict__ q,
    const float* __restrict__ g_w1, const float* __restrict__ g_b1,
    const float* __restrict__ g_w2,
    const float* __restrict__ qe_w1, const float* __restrict__ qe_b1,
    const float* __restrict__ qe_w2, const float* __restrict__ qe_b2,
    float* __restrict__ U, float* __restrict__ V,
    float* __restrict__ c0, float* __restrict__ qexp,
    short* __restrict__ w2s, float* __restrict__ accb)
{
    const int blk = blockIdx.x, t = threadIdx.x;

    if (blk < 64) {
        __shared__ float xs[1024];          // 16 rows x 64
        const int rg = blk >> 1, half = blk & 1;
        const int r0 = rg << 4;
        #pragma unroll
        for (int i = 0; i < 4; ++i) {
            int idx = i * 256 + t;
            xs[idx] = x[(r0 << 6) + idx];
        }
        float w[64];
        #pragma unroll
        for (int k = 0; k < 64; ++k)
            w[k] = g_w1[(half * 64 + k) * 256 + t];
        __syncthreads();
        float* dst = half ? V : U;
        #pragma unroll 2
        for (int r = 0; r < 16; ++r) {
            float a0 = 0.f, a1 = 0.f, a2 = 0.f, a3 = 0.f;
            #pragma unroll
            for (int k = 0; k < 64; k += 4) {
                const float4 xv = *(const float4*)&xs[r * 64 + k];
                a0 += xv.x * w[k + 0];
                a1 += xv.y * w[k + 1];
                a2 += xv.z * w[k + 2];
                a3 += xv.w * w[k + 3];
            }
            dst[(r0 + r) * 256 + t] = (a0 + a1) + (a2 + a3);
        }
    } else if (blk == 64) {
        __shared__ float sbuf[64];
        __shared__ float qh[256];
        if (t < 64) sbuf[t] = q[t];
        __syncthreads();
        float cc = g_b1[t], hh = qe_b1[t];
        #pragma unroll 4
        for (int k = 0; k < 64; ++k) {
            float qv = sbuf[k];
            cc += qv * g_w1[(128 + k) * 256 + t];
            hh += qv * qe_w1[k * 256 + t];
        }
        c0[t] = cc;
        qh[t] = fmaxf(hh, 0.f);
        __syncthreads();
        float qe = qe_b2[t];
        #pragma unroll 4
        for (int k = 0; k < 256; ++k) qe += qh[k] * qe_w2[k * 256 + t];
        qexp[t] = fmaxf(qe, 0.f);
    } else if (blk < 97) {
        // w2s: read 8 consecutive g_w2 elems (coalesced), scatter-write bf16
        const int S0 = (blk - 65) * 2048 + t * 8;
        const float4 wA = *(const float4*)&g_w2[S0];
        const float4 wB = *(const float4*)&g_w2[S0 + 4];
        float wv8[8] = {wA.x, wA.y, wA.z, wA.w, wB.x, wB.y, wB.z, wB.w};
        #pragma unroll
        for (int i = 0; i < 8; ++i) {
            const int S = S0 + i;
            const int k = S >> 8, col = S & 255;
            const int wv = col >> 6, n = (col >> 4) & 3, l15 = col & 15;
            const int kk = k >> 5, g = (k >> 3) & 3, e = k & 7;
            const int lane = g * 16 + l15;
            w2s[((((wv * 8 + kk) * 4 + n) * 64 + lane) << 3) + e] = f2bf(wv8[i]);
        }
    } else {
        const int total = NSLOT * 257;
        int off = (blk - 97) * 2048 + t * 8;
        #pragma unroll
        for (int i = 0; i < 8; ++i)
            if (off + i < total) accb[off + i] = 0.f;
    }
}

// ---------------------------------------------------------------------------
// K2: one block per (a, 64-row b-chunk): a = bid>>3, b0 = (bid&7)*64.
// 4096 blocks, 4 waves, 4 blocks/CU. B fragments streamed per-use from
// swizzled w2s (coalesced, L2-hot). 2 barriers/block. g_b2 folded into acc init.
// ---------------------------------------------------------------------------
__global__ __launch_bounds__(256, 4) void rn_k2(
    const float* __restrict__ U, const float* __restrict__ V,
    const float* __restrict__ c0, const float* __restrict__ qexp,
    const short* __restrict__ w2s, const float* __restrict__ g_b2,
    float* __restrict__ accb)
{
    __shared__ short hT[64][264];          // 528B pitch: b128 reads conflict-free
    __shared__ float srowT[64][4];         // [row][wave]

    const int bid = blockIdx.x;
    const int a   = bid >> 3;
    const int b0  = (bid & 7) << 6;
    const int tid = threadIdx.x;
    const int wave = tid >> 6, lane = tid & 63;
    const int l15 = lane & 15, g = lane >> 4;
    const int col0 = wave << 6;

    // ---- build h tile: 64 rows x 256 cols (bf16), no staging barrier ----
    {
        const int c4 = tid & 63;
        const int r0 = tid >> 6;
        const float4 vv  = *(const float4*)&V[a * 256 + c4 * 4];
        const float4 cc  = *(const float4*)&c0[c4 * 4];
        const float4 vcv = make_float4(vv.x + cc.x, vv.y + cc.y,
                                       vv.z + cc.z, vv.w + cc.w);
        #pragma unroll
        for (int it = 0; it < 16; ++it) {
            int row = r0 + it * 4;
            float4 uu = *(const float4*)&U[(b0 + row) * 256 + c4 * 4];
            __hip_bfloat162 p0 = __float22bfloat162_rn(
                make_float2(fmaxf(uu.x + vcv.x, 0.f), fmaxf(uu.y + vcv.y, 0.f)));
            __hip_bfloat162 p1 = __float22bfloat162_rn(
                make_float2(fmaxf(uu.z + vcv.z, 0.f), fmaxf(uu.w + vcv.w, 0.f)));
            uint2 st;
            st.x = *reinterpret_cast<unsigned*>(&p0);
            st.y = *reinterpret_cast<unsigned*>(&p1);
            *reinterpret_cast<uint2*>(&hT[row][c4 * 4]) = st;
        }
    }

    float qe[4], b2c[4];
    #pragma unroll
    for (int n = 0; n < 4; ++n) {
        int col = col0 + n * 16 + l15;
        qe[n]  = qexp[col];
        b2c[n] = g_b2[col];
    }
    __syncthreads();                        // hT ready

    // ---- MFMA: r = h @ W2 + b2 (bias via acc init), B streamed from L2 ----
    f32x4 acc[4][4];
    #pragma unroll
    for (int m = 0; m < 4; ++m)
        #pragma unroll
        for (int n = 0; n < 4; ++n)
            acc[m][n] = (f32x4){b2c[n], b2c[n], b2c[n], b2c[n]};

    #pragma unroll
    for (int kk = 0; kk < 8; ++kk) {
        const int koff = kk * 32 + g * 8;
        s16x8 bfr[4];
        #pragma unroll
        for (int n = 0; n < 4; ++n)
            bfr[n] = *(const s16x8*)&w2s[((wave << 14) + (((kk * 4 + n) << 9))) + (lane << 3)];
        s16x8 afr[4];
        #pragma unroll
        for (int m = 0; m < 4; ++m)
            afr[m] = *(const s16x8*)&hT[m * 16 + l15][koff];
        #pragma unroll
        for (int m = 0; m < 4; ++m)
            #pragma unroll
            for (int n = 0; n < 4; ++n)
                acc[m][n] = __builtin_amdgcn_mfma_f32_16x16x32_bf16(
                    afr[m], bfr[n], acc[m][n], 0, 0, 0);
    }

    // ---- epilogue: relu, scores, exp weights, weighted sums ----
    #pragma unroll
    for (int m = 0; m < 4; ++m)
        #pragma unroll
        for (int n = 0; n < 4; ++n)
            #pragma unroll
            for (int j = 0; j < 4; ++j)
                acc[m][n][j] = fmaxf(acc[m][n][j], 0.f);

    // per-wave score partials (this wave's 64 cols) for all 64 rows
    #pragma unroll
    for (int m = 0; m < 4; ++m) {
        #pragma unroll
        for (int j = 0; j < 4; ++j) {
            float sp = 0.f;
            #pragma unroll
            for (int n = 0; n < 4; ++n) sp += acc[m][n][j] * qe[n];
            sp += __shfl_xor(sp, 1);
            sp += __shfl_xor(sp, 2);
            sp += __shfl_xor(sp, 4);
            sp += __shfl_xor(sp, 8);
            if (l15 == 0) srowT[m * 16 + g * 4 + j][wave] = sp;
        }
    }
    __syncthreads();                        // srowT ready

    // every wave: full row scores -> exp weights (float4 broadcast reads)
    float wrow[4][4];
    #pragma unroll
    for (int m = 0; m < 4; ++m)
        #pragma unroll
        for (int j = 0; j < 4; ++j) {
            const float4 s4 = *(const float4*)&srowT[m * 16 + g * 4 + j][0];
            wrow[m][j] = __expf(s4.x + s4.y + s4.z + s4.w);  // s >= 0, bounded
        }

    const int slot = bid & (NSLOT - 1);
    if (wave == 0) {
        float ls = 0.f;
        #pragma unroll
        for (int m = 0; m < 4; ++m)
            #pragma unroll
            for (int j = 0; j < 4; ++j) ls += wrow[m][j];
        ls += __shfl_xor(ls, 16);
        ls += __shfl_xor(ls, 32);           // sum over the 4 row-groups
        if (lane == 0) atomicAdd(&accb[slot * 257 + 256], ls);
    }

    #pragma unroll
    for (int n = 0; n < 4; ++n) {
        float wv = 0.f;
        #pragma unroll
        for (int m = 0; m < 4; ++m)
            #pragma unroll
            for (int j = 0; j < 4; ++j)
                wv += wrow[m][j] * acc[m][n][j];
        wv += __shfl_xor(wv, 16);
        wv += __shfl_xor(wv, 32);
        if (lane < 16) atomicAdd(&accb[slot * 257 + col0 + n * 16 + lane], wv);
    }
}

// ---------------------------------------------------------------------------
// K4: merge NSLOT slots -> embedding -> f MLP -> out[64]
// 1024 threads: 4-way K-split per layer + LDS reduce (parallel weight loads).
// ---------------------------------------------------------------------------
__global__ __launch_bounds__(1024) void rn_k4(
    const float* __restrict__ accb,
    const float* __restrict__ f_w1, const float* __restrict__ f_b1,
    const float* __restrict__ f_w2, const float* __restrict__ f_b2,
    float* __restrict__ out)
{
    __shared__ float part[4][256];
    __shared__ float emb[256];
    __shared__ float fh[256];
    __shared__ float lsa[128];
    const int t   = threadIdx.x;
    const int col = t & 255;
    const int sl  = t >> 8;                 // 0..3

    // slot merge (each (sl,col) sums 32 slots)
    float v = 0.f;
    #pragma unroll 8
    for (int s = sl; s < NSLOT; s += 4) v += accb[s * 257 + col];
    part[sl][col] = v;
    if (t < 128) lsa[t] = accb[t * 257 + 256];
    __syncthreads();

    if (sl == 0) {
        float ls = 0.f;
        #pragma unroll 8
        for (int s = 0; s < 128; ++s) ls += lsa[s];     // broadcast reads
        emb[col] = (part[0][col] + part[1][col] + part[2][col] + part[3][col]) / ls;
    }
    __syncthreads();

    // f layer 1: K-split by sl
    {
        float h = 0.f;
        const int k0 = sl << 6;
        #pragma unroll 8
        for (int k = 0; k < 64; ++k)
            h += emb[k0 + k] * f_w1[(k0 + k) * 256 + col];
        part[sl][col] = h;
    }
    __syncthreads();
    if (sl == 0)
        fh[col] = fmaxf(part[0][col] + part[1][col] + part[2][col] + part[3][col]
                        + f_b1[col], 0.f);
    __syncthreads();

    // f layer 2: out 64 cols, K-split by t>>6 (threads 0..255)
    if (t < 256) {
        const int oc = t & 63, ks = t >> 6;
        float o = 0.f;
        const int k0 = ks << 6;
        #pragma unroll 8
        for (int k = 0; k < 64; ++k)
            o += fh[k0 + k] * f_w2[(k0 + k) * 64 + oc];
        part[ks][oc] = o;
    }
    __syncthreads();
    if (t < 64)
        out[t] = part[0][t] + part[1][t] + part[2][t] + part[3][t] + f_b2[t];
}

extern "C" void kernel_launch(void* const* d_in, const int* in_sizes, int n_in,
                              void* d_out, int out_size, void* d_ws, size_t ws_size,
                              hipStream_t stream) {
    const float* x     = (const float*)d_in[0];
    const float* q     = (const float*)d_in[1];
    const float* g_w1  = (const float*)d_in[2];
    const float* g_b1  = (const float*)d_in[3];
    const float* g_w2  = (const float*)d_in[4];
    const float* g_b2  = (const float*)d_in[5];
    const float* qe_w1 = (const float*)d_in[6];
    const float* qe_b1 = (const float*)d_in[7];
    const float* qe_w2 = (const float*)d_in[8];
    const float* qe_b2 = (const float*)d_in[9];
    const float* f_w1  = (const float*)d_in[10];
    const float* f_b1  = (const float*)d_in[11];
    const float* f_w2  = (const float*)d_in[12];
    const float* f_b2  = (const float*)d_in[13];

    float* wsf  = (float*)d_ws;
    float* U    = wsf;                     // 512*256 f32
    float* V    = wsf + 131072;            // 512*256 f32
    float* c0   = wsf + 262144;            // 256
    float* qexp = wsf + 262400;            // 256
    short* w2s  = (short*)(wsf + 262656);  // 256*256 bf16 (swizzled)
    float* accb = wsf + 295424;            // NSLOT slots * 257 floats

    // k1 blocks: 64 UV-GEMM + 1 q + 32 w2s + 17 zeroing = 114
    hipLaunchKernelGGL(rn_k1, dim3(114), dim3(256), 0, stream,
                       x, q, g_w1, g_b1, g_w2, qe_w1, qe_b1, qe_w2, qe_b2,
                       U, V, c0, qexp, w2s, accb);
    hipLaunchKernelGGL(rn_k2, dim3(4096), dim3(256), 0, stream,
                       U, V, c0, qexp, (const short*)w2s, g_b2, accb);
    hipLaunchKernelGGL(rn_k4, dim3(1), dim3(1024), 0, stream,
                       accb, f_w1, f_b1, f_w2, f_b2, (float*)d_out);
}

// Round 9
// 70.702 us; speedup vs baseline: 2.4625x; 1.0266x over previous
//
#include <hip/hip_runtime.h>
#include <hip/hip_bf16.h>

typedef __attribute__((ext_vector_type(8))) short s16x8;
typedef __attribute__((ext_vector_type(4))) float f32x4;

#define NSLOT 128

__device__ __forceinline__ short f2bf(float f) {
    union { float f; unsigned u; } c; c.f = f;
    unsigned u = c.u;
    return (short)((u + 0x7fffu + ((u >> 16) & 1u)) >> 16);  // RNE
}
__device__ __forceinline__ unsigned pk2(float lo, float hi) {
    __hip_bfloat162 p = __float22bfloat162_rn(make_float2(lo, hi));
    return *reinterpret_cast<unsigned*>(&p);
}
// sum over the 16-lane DPP row via row_ror butterfly (VALU only, no DS pipe)
__device__ __forceinline__ float rowsum16(float x) {
    union { float f; int i; } a, b;
    a.f = x;
    b.i = __builtin_amdgcn_mov_dpp(a.i, 0x121, 0xf, 0xf, true); a.f += b.f; // ror:1
    b.i = __builtin_amdgcn_mov_dpp(a.i, 0x122, 0xf, 0xf, true); a.f += b.f; // ror:2
    b.i = __builtin_amdgcn_mov_dpp(a.i, 0x124, 0xf, 0xf, true); a.f += b.f; // ror:4
    b.i = __builtin_amdgcn_mov_dpp(a.i, 0x128, 0xf, 0xf, true); a.f += b.f; // ror:8
    return a.f;
}

// ---------------------------------------------------------------------------
// K1: precompute, GEMM-restructured (no redundant W1 re-reads).
//   blocks 0..63:   UV GEMM (W1 col-slice in regs, x-tile in LDS)
//   block 64:       c0 = q@W1q + g_b1 ; q_exp = relu(relu(q@qe_w1+b1)@qe_w2+b2)
//   blocks 65..96:  w2s swizzle (coalesced reads, scatter bf16 writes)
//   blocks 97..113: zero accb
// w2s layout: w2s[(((wv*8+kk)*4+n)*64+lane)*8+e] = bf16(g_w2[k*256+col]),
//   col = wv*64+n*16+(lane&15), k = kk*32+(lane>>4)*8+e
// ---------------------------------------------------------------------------
__global__ __launch_bounds__(256) void rn_k1(
    const float* __restrict__ x, const float* __restrict__ q,
    const float* __restrict__ g_w1, const float* __restrict__ g_b1,
    const float* __restrict__ g_w2,
    const float* __restrict__ qe_w1, const float* __restrict__ qe_b1,
    const float* __restrict__ qe_w2, const float* __restrict__ qe_b2,
    float* __restrict__ U, float* __restrict__ V,
    float* __restrict__ c0, float* __restrict__ qexp,
    short* __restrict__ w2s, float* __restrict__ accb)
{
    const int blk = blockIdx.x, t = threadIdx.x;

    if (blk < 64) {
        __shared__ float xs[1024];          // 16 rows x 64
        const int rg = blk >> 1, half = blk & 1;
        const int r0 = rg << 4;
        #pragma unroll
        for (int i = 0; i < 4; ++i) {
            int idx = i * 256 + t;
            xs[idx] = x[(r0 << 6) + idx];
        }
        float w[64];
        #pragma unroll
        for (int k = 0; k < 64; ++k)
            w[k] = g_w1[(half * 64 + k) * 256 + t];
        __syncthreads();
        float* dst = half ? V : U;
        #pragma unroll 2
        for (int r = 0; r < 16; ++r) {
            float a0 = 0.f, a1 = 0.f, a2 = 0.f, a3 = 0.f;
            #pragma unroll
            for (int k = 0; k < 64; k += 4) {
                const float4 xv = *(const float4*)&xs[r * 64 + k];
                a0 += xv.x * w[k + 0];
                a1 += xv.y * w[k + 1];
                a2 += xv.z * w[k + 2];
                a3 += xv.w * w[k + 3];
            }
            dst[(r0 + r) * 256 + t] = (a0 + a1) + (a2 + a3);
        }
    } else if (blk == 64) {
        __shared__ float sbuf[64];
        __shared__ float qh[256];
        if (t < 64) sbuf[t] = q[t];
        __syncthreads();
        float cc = g_b1[t], hh = qe_b1[t];
        #pragma unroll 4
        for (int k = 0; k < 64; ++k) {
            float qv = sbuf[k];
            cc += qv * g_w1[(128 + k) * 256 + t];
            hh += qv * qe_w1[k * 256 + t];
        }
        c0[t] = cc;
        qh[t] = fmaxf(hh, 0.f);
        __syncthreads();
        float qe = qe_b2[t];
        #pragma unroll 4
        for (int k = 0; k < 256; ++k) qe += qh[k] * qe_w2[k * 256 + t];
        qexp[t] = fmaxf(qe, 0.f);
    } else if (blk < 97) {
        const int S0 = (blk - 65) * 2048 + t * 8;
        const float4 wA = *(const float4*)&g_w2[S0];
        const float4 wB = *(const float4*)&g_w2[S0 + 4];
        float wv8[8] = {wA.x, wA.y, wA.z, wA.w, wB.x, wB.y, wB.z, wB.w};
        #pragma unroll
        for (int i = 0; i < 8; ++i) {
            const int S = S0 + i;
            const int k = S >> 8, col = S & 255;
            const int wv = col >> 6, n = (col >> 4) & 3, l15 = col & 15;
            const int kk = k >> 5, g = (k >> 3) & 3, e = k & 7;
            const int lane = g * 16 + l15;
            w2s[((((wv * 8 + kk) * 4 + n) * 64 + lane) << 3) + e] = f2bf(wv8[i]);
        }
    } else {
        const int total = NSLOT * 257;
        int off = (blk - 97) * 2048 + t * 8;
        #pragma unroll
        for (int i = 0; i < 8; ++i)
            if (off + i < total) accb[off + i] = 0.f;
    }
}

// ---------------------------------------------------------------------------
// K2: one block per (a, 64-row b-chunk). 4096 blocks, 4 waves, 3 blocks/CU.
// K-split pipeline: build h cols 0..127 -> bar -> { MFMA kk0..3 ; build cols
// 128..255 from register-staged U (VALU overlaps the busy MFMA pipe) } -> bar
// -> MFMA kk4..7 -> DPP epilogue. B loaded once per kk (K-split, no dup).
// ---------------------------------------------------------------------------
__global__ __launch_bounds__(256, 3) void rn_k2(
    const float* __restrict__ U, const float* __restrict__ V,
    const float* __restrict__ c0, const float* __restrict__ qexp,
    const short* __restrict__ w2s, const float* __restrict__ g_b2,
    float* __restrict__ accb)
{
    __shared__ short hT[64][264];          // 528B pitch: b128 reads conflict-light
    __shared__ float srowT[64][4];         // [row][wave]

    const int bid = blockIdx.x;
    const int a   = bid >> 3;
    const int b0  = (bid & 7) << 6;
    const int tid = threadIdx.x;
    const int wave = tid >> 6, lane = tid & 63;
    const int l15 = lane & 15, g = lane >> 4;
    const int col0 = wave << 6;

    // build-thread coords: 32 float4-cols per half, 8 row-groups
    const int c32 = tid & 31;
    const int r0  = tid >> 5;              // 0..7

    float qe[4], b2c[4];
    #pragma unroll
    for (int n = 0; n < 4; ++n) {
        int col = col0 + n * 16 + l15;
        qe[n]  = qexp[col];
        b2c[n] = g_b2[col];
    }
    float4 vcv0, vcv1;
    {
        const float4 vA = *(const float4*)&V[a * 256 + c32 * 4];
        const float4 cA = *(const float4*)&c0[c32 * 4];
        vcv0 = make_float4(vA.x + cA.x, vA.y + cA.y, vA.z + cA.z, vA.w + cA.w);
        const float4 vB = *(const float4*)&V[a * 256 + 128 + c32 * 4];
        const float4 cB = *(const float4*)&c0[128 + c32 * 4];
        vcv1 = make_float4(vB.x + cB.x, vB.y + cB.y, vB.z + cB.z, vB.w + cB.w);
    }

    // ---- prologue: register-stage half0 U, build half0 (cols 0..127) ----
    float4 ur[8];
    #pragma unroll
    for (int it = 0; it < 8; ++it)
        ur[it] = *(const float4*)&U[(b0 + r0 + it * 8) * 256 + c32 * 4];
    #pragma unroll
    for (int it = 0; it < 8; ++it) {
        const int row = r0 + it * 8;
        uint2 st;
        st.x = pk2(fmaxf(ur[it].x + vcv0.x, 0.f), fmaxf(ur[it].y + vcv0.y, 0.f));
        st.y = pk2(fmaxf(ur[it].z + vcv0.z, 0.f), fmaxf(ur[it].w + vcv0.w, 0.f));
        *reinterpret_cast<uint2*>(&hT[row][c32 * 4]) = st;
    }
    // issue half1 U loads (consumed after MFMA phase 0)
    #pragma unroll
    for (int it = 0; it < 8; ++it)
        ur[it] = *(const float4*)&U[(b0 + r0 + it * 8) * 256 + 128 + c32 * 4];
    __syncthreads();                        // half0 ready

    f32x4 acc[4][4];
    #pragma unroll
    for (int m = 0; m < 4; ++m)
        #pragma unroll
        for (int n = 0; n < 4; ++n)
            acc[m][n] = (f32x4){b2c[n], b2c[n], b2c[n], b2c[n]};

    // ---- MFMA phase 0: kk = 0..3 (K 0..127) ----
    __builtin_amdgcn_s_setprio(1);
    #pragma unroll
    for (int kk = 0; kk < 4; ++kk) {
        const int koff = kk * 32 + g * 8;
        s16x8 bfr[4];
        #pragma unroll
        for (int n = 0; n < 4; ++n)
            bfr[n] = *(const s16x8*)&w2s[(wave << 14) + ((kk * 4 + n) << 9) + (lane << 3)];
        s16x8 afr[4];
        #pragma unroll
        for (int m = 0; m < 4; ++m)
            afr[m] = *(const s16x8*)&hT[m * 16 + l15][koff];
        #pragma unroll
        for (int m = 0; m < 4; ++m)
            #pragma unroll
            for (int n = 0; n < 4; ++n)
                acc[m][n] = __builtin_amdgcn_mfma_f32_16x16x32_bf16(
                    afr[m], bfr[n], acc[m][n], 0, 0, 0);
    }
    __builtin_amdgcn_s_setprio(0);

    // ---- build half1 (cols 128..255) while MFMA pipe drains ----
    #pragma unroll
    for (int it = 0; it < 8; ++it) {
        const int row = r0 + it * 8;
        uint2 st;
        st.x = pk2(fmaxf(ur[it].x + vcv1.x, 0.f), fmaxf(ur[it].y + vcv1.y, 0.f));
        st.y = pk2(fmaxf(ur[it].z + vcv1.z, 0.f), fmaxf(ur[it].w + vcv1.w, 0.f));
        *reinterpret_cast<uint2*>(&hT[row][128 + c32 * 4]) = st;
    }
    __syncthreads();                        // half1 ready

    // ---- MFMA phase 1: kk = 4..7 (K 128..255) ----
    __builtin_amdgcn_s_setprio(1);
    #pragma unroll
    for (int kk = 4; kk < 8; ++kk) {
        const int koff = kk * 32 + g * 8;
        s16x8 bfr[4];
        #pragma unroll
        for (int n = 0; n < 4; ++n)
            bfr[n] = *(const s16x8*)&w2s[(wave << 14) + ((kk * 4 + n) << 9) + (lane << 3)];
        s16x8 afr[4];
        #pragma unroll
        for (int m = 0; m < 4; ++m)
            afr[m] = *(const s16x8*)&hT[m * 16 + l15][koff];
        #pragma unroll
        for (int m = 0; m < 4; ++m)
            #pragma unroll
            for (int n = 0; n < 4; ++n)
                acc[m][n] = __builtin_amdgcn_mfma_f32_16x16x32_bf16(
                    afr[m], bfr[n], acc[m][n], 0, 0, 0);
    }
    __builtin_amdgcn_s_setprio(0);

    // ---- epilogue: relu, DPP score reduce, exp weights, weighted sums ----
    #pragma unroll
    for (int m = 0; m < 4; ++m)
        #pragma unroll
        for (int n = 0; n < 4; ++n)
            #pragma unroll
            for (int j = 0; j < 4; ++j)
                acc[m][n][j] = fmaxf(acc[m][n][j], 0.f);

    #pragma unroll
    for (int m = 0; m < 4; ++m) {
        #pragma unroll
        for (int j = 0; j < 4; ++j) {
            float sp = acc[m][0][j] * qe[0] + acc[m][1][j] * qe[1]
                     + acc[m][2][j] * qe[2] + acc[m][3][j] * qe[3];
            sp = rowsum16(sp);              // VALU DPP butterfly, all 16 lanes
            if (l15 == 0) srowT[m * 16 + g * 4 + j][wave] = sp;
        }
    }
    __syncthreads();                        // srowT ready

    float wrow[4][4];
    #pragma unroll
    for (int m = 0; m < 4; ++m)
        #pragma unroll
        for (int j = 0; j < 4; ++j) {
            const float4 s4 = *(const float4*)&srowT[m * 16 + g * 4 + j][0];
            wrow[m][j] = __expf(s4.x + s4.y + s4.z + s4.w);  // s >= 0, bounded
        }

    const int slot = bid & (NSLOT - 1);
    if (wave == 0) {
        float ls = 0.f;
        #pragma unroll
        for (int m = 0; m < 4; ++m)
            #pragma unroll
            for (int j = 0; j < 4; ++j) ls += wrow[m][j];
        ls += __shfl_xor(ls, 16);
        ls += __shfl_xor(ls, 32);
        if (lane == 0) atomicAdd(&accb[slot * 257 + 256], ls);
    }

    #pragma unroll
    for (int n = 0; n < 4; ++n) {
        float wv = 0.f;
        #pragma unroll
        for (int m = 0; m < 4; ++m)
            #pragma unroll
            for (int j = 0; j < 4; ++j)
                wv += wrow[m][j] * acc[m][n][j];
        wv += __shfl_xor(wv, 16);
        wv += __shfl_xor(wv, 32);
        if (lane < 16) atomicAdd(&accb[slot * 257 + col0 + n * 16 + lane], wv);
    }
}

// ---------------------------------------------------------------------------
// K4: merge NSLOT slots -> embedding -> f MLP -> out[64]
// ---------------------------------------------------------------------------
__global__ __launch_bounds__(1024) void rn_k4(
    const float* __restrict__ accb,
    const float* __restrict__ f_w1, const float* __restrict__ f_b1,
    const float* __restrict__ f_w2, const float* __restrict__ f_b2,
    float* __restrict__ out)
{
    __shared__ float part[4][256];
    __shared__ float emb[256];
    __shared__ float fh[256];
    __shared__ float lsa[128];
    const int t   = threadIdx.x;
    const int col = t & 255;
    const int sl  = t >> 8;                 // 0..3

    float v = 0.f;
    #pragma unroll 8
    for (int s = sl; s < NSLOT; s += 4) v += accb[s * 257 + col];
    part[sl][col] = v;
    if (t < 128) lsa[t] = accb[t * 257 + 256];
    __syncthreads();

    if (sl == 0) {
        float ls = 0.f;
        #pragma unroll 8
        for (int s = 0; s < 128; ++s) ls += lsa[s];
        emb[col] = (part[0][col] + part[1][col] + part[2][col] + part[3][col]) / ls;
    }
    __syncthreads();

    {
        float h = 0.f;
        const int k0 = sl << 6;
        #pragma unroll 8
        for (int k = 0; k < 64; ++k)
            h += emb[k0 + k] * f_w1[(k0 + k) * 256 + col];
        part[sl][col] = h;
    }
    __syncthreads();
    if (sl == 0)
        fh[col] = fmaxf(part[0][col] + part[1][col] + part[2][col] + part[3][col]
                        + f_b1[col], 0.f);
    __syncthreads();

    if (t < 256) {
        const int oc = t & 63, ks = t >> 6;
        float o = 0.f;
        const int k0 = ks << 6;
        #pragma unroll 8
        for (int k = 0; k < 64; ++k)
            o += fh[k0 + k] * f_w2[(k0 + k) * 64 + oc];
        part[ks][oc] = o;
    }
    __syncthreads();
    if (t < 64)
        out[t] = part[0][t] + part[1][t] + part[2][t] + part[3][t] + f_b2[t];
}

extern "C" void kernel_launch(void* const* d_in, const int* in_sizes, int n_in,
                              void* d_out, int out_size, void* d_ws, size_t ws_size,
                              hipStream_t stream) {
    const float* x     = (const float*)d_in[0];
    const float* q     = (const float*)d_in[1];
    const float* g_w1  = (const float*)d_in[2];
    const float* g_b1  = (const float*)d_in[3];
    const float* g_w2  = (const float*)d_in[4];
    const float* g_b2  = (const float*)d_in[5];
    const float* qe_w1 = (const float*)d_in[6];
    const float* qe_b1 = (const float*)d_in[7];
    const float* qe_w2 = (const float*)d_in[8];
    const float* qe_b2 = (const float*)d_in[9];
    const float* f_w1  = (const float*)d_in[10];
    const float* f_b1  = (const float*)d_in[11];
    const float* f_w2  = (const float*)d_in[12];
    const float* f_b2  = (const float*)d_in[13];

    float* wsf  = (float*)d_ws;
    float* U    = wsf;                     // 512*256 f32
    float* V    = wsf + 131072;            // 512*256 f32
    float* c0   = wsf + 262144;            // 256
    float* qexp = wsf + 262400;            // 256
    short* w2s  = (short*)(wsf + 262656);  // 256*256 bf16 (swizzled)
    float* accb = wsf + 295424;            // NSLOT slots * 257 floats

    hipLaunchKernelGGL(rn_k1, dim3(114), dim3(256), 0, stream,
                       x, q, g_w1, g_b1, g_w2, qe_w1, qe_b1, qe_w2, qe_b2,
                       U, V, c0, qexp, w2s, accb);
    hipLaunchKernelGGL(rn_k2, dim3(4096), dim3(256), 0, stream,
                       U, V, c0, qexp, (const short*)w2s, g_b2, accb);
    hipLaunchKernelGGL(rn_k4, dim3(1), dim3(1024), 0, stream,
                       accb, f_w1, f_b1, f_w2, f_b2, (float*)d_out);
}